// Round 5
// baseline (96.114 us; speedup 1.0000x reference)
//
#include <hip/hip_runtime.h>

#define C_IN 256
#define HC   128
#define HW   4096

#define SX   260                 // u16 stride of X rows (mult of 4 -> 8B-aligned u16x4 writes)
#define SH   132                 // u16 stride of H rows
#define XREG (16 * SX)           // u16 per wave LDS region (8320 B)

typedef __attribute__((ext_vector_type(8))) short short8;
typedef __attribute__((ext_vector_type(4))) short short4v;
typedef __attribute__((ext_vector_type(4))) float f32x4;
typedef __attribute__((ext_vector_type(4))) unsigned short u16x4;

__device__ __forceinline__ unsigned short f2bf(float f) {
    union { float f; unsigned int u; } v; v.f = f;
    return (unsigned short)((v.u + 0x7FFFu + ((v.u >> 16) & 1u)) >> 16);
}

// tanh-form GELU: max |err| vs exact-erf gelu ~3e-3, far under threshold.
__device__ __forceinline__ float gelu_f(float v) {
    const float u = v * (0.7978845608028654f + 0.035677408136300125f * v * v);
    const float e = __expf(2.0f * u);
    const float t = 1.0f - 2.0f * __builtin_amdgcn_rcpf(e + 1.0f);
    return 0.5f * v * (1.0f + t);
}

// Wave-local LDS ordering (region is private to this wave after the one barrier).
__device__ __forceinline__ void wave_lds_fence() {
    asm volatile("s_waitcnt lgkmcnt(0)" ::: "memory");
}

__global__ void convert_weights(const float* __restrict__ W1, const float* __restrict__ W2,
                                unsigned short* __restrict__ W1b, unsigned short* __restrict__ W2b) {
    int i = blockIdx.x * blockDim.x + threadIdx.x;
    if (i < HC * C_IN) { W1b[i] = f2bf(W1[i]); W2b[i] = f2bf(W2[i]); }
}

template<bool USE_WS>
__global__ __launch_bounds__(256, 4) void fused_mlp(
    const float* __restrict__ x,
    const float* __restrict__ W1, const float* __restrict__ b1,
    const float* __restrict__ g1, const float* __restrict__ be1,
    const float* __restrict__ W2, const float* __restrict__ b2,
    const float* __restrict__ g2, const float* __restrict__ be2,
    const unsigned short* __restrict__ W1b, const unsigned short* __restrict__ W2b,
    float* __restrict__ out)
{
    __shared__ alignas(16) unsigned short Xs[4 * XREG];   // 33280 B

    const int tid = threadIdx.x;
    const int wv  = tid >> 6;
    const int l   = tid & 63;
    const int l15 = l & 15;     // pixel within wave tile
    const int h   = l >> 4;     // k-group / channel-subquad 0..3

    const int bid = blockIdx.x;
    const int b   = bid >> 6;               // 64 blocks per image
    const int p0  = (bid & 63) * 64;        // block pixel base (64 px)
    const float* xb = x   + (size_t)b * (C_IN * HW) + p0;
    float*       ob = out + (size_t)b * (C_IN * HW) + p0;

    // ---- block-cooperative staging: fp32 [c][p] -> bf16 LDS [wave][px][c] ----
    {
        const int g  = tid & 15;    // pixel quad 0..15 (px 4g..4g+3)
        const int cq = tid >> 4;    // channel quad 0..15
        f32x4 v[16];
        #pragma unroll
        for (int it = 0; it < 4; ++it) {
            const int c0 = it * 64 + cq * 4;
            #pragma unroll
            for (int j = 0; j < 4; ++j)
                v[it * 4 + j] = *reinterpret_cast<const f32x4*>(xb + (size_t)(c0 + j) * HW + g * 4);
        }
        #pragma unroll
        for (int it = 0; it < 4; ++it) {
            const int c0 = it * 64 + cq * 4;
            #pragma unroll
            for (int jj = 0; jj < 4; ++jj) {
                const int px = g * 4 + jj;
                u16x4 pk;
                #pragma unroll
                for (int j = 0; j < 4; ++j) pk[j] = f2bf(v[it * 4 + j][jj]);
                *reinterpret_cast<u16x4*>(&Xs[(px >> 4) * XREG + (px & 15) * SX + c0]) = pk;
            }
        }
    }
    __syncthreads();   // the ONLY block barrier

    unsigned short* Xw = &Xs[wv * XREG];
    const f32x4 vzero = {0.f, 0.f, 0.f, 0.f};

    // ---- GEMM1: H(128 x 16px) = W1(128x256) @ Xw(256x16) ----
    f32x4 acc1[8];
    #pragma unroll
    for (int m = 0; m < 8; ++m) acc1[m] = vzero;

    #pragma unroll
    for (int ks = 0; ks < 8; ++ks) {
        const int kb = ks * 32 + h * 8;
        const short4v blo = *reinterpret_cast<const short4v*>(&Xw[l15 * SX + kb]);
        const short4v bhi = *reinterpret_cast<const short4v*>(&Xw[l15 * SX + kb + 4]);
        const short8 bf = __builtin_shufflevector(blo, bhi, 0,1,2,3,4,5,6,7);
        short8 a[8];
        #pragma unroll
        for (int m = 0; m < 8; ++m) {
            const int row = m * 16 + l15;
            if constexpr (USE_WS) {
                a[m] = *reinterpret_cast<const short8*>(W1b + (size_t)row * C_IN + kb);
            } else {
                const float* wp = W1 + (size_t)row * C_IN + kb;
                const f32x4 f0 = *reinterpret_cast<const f32x4*>(wp);
                const f32x4 f1 = *reinterpret_cast<const f32x4*>(wp + 4);
                #pragma unroll
                for (int e = 0; e < 4; ++e) { a[m][e] = (short)f2bf(f0[e]); a[m][4+e] = (short)f2bf(f1[e]); }
            }
        }
        #pragma unroll
        for (int m = 0; m < 8; ++m)
            acc1[m] = __builtin_amdgcn_mfma_f32_16x16x32_bf16(a[m], bf, acc1[m], 0, 0, 0);
    }
    wave_lds_fence();   // Xw reads complete before Hw (alias) writes

    // ---- bias1 + wave-local LN1 (lanes l15+16h jointly hold all 128 ch of px l15) ----
    float s1 = 0.f, q1 = 0.f;
    #pragma unroll
    for (int m = 0; m < 8; ++m) {
        acc1[m] += *reinterpret_cast<const f32x4*>(b1 + m * 16 + h * 4);
        #pragma unroll
        for (int r = 0; r < 4; ++r) { const float v = acc1[m][r]; s1 += v; q1 += v * v; }
    }
    s1 += __shfl_xor(s1, 16); s1 += __shfl_xor(s1, 32);
    q1 += __shfl_xor(q1, 16); q1 += __shfl_xor(q1, 32);
    const float mean1 = s1 * (1.0f / HC);
    const float rstd1 = rsqrtf(q1 * (1.0f / HC) - mean1 * mean1 + 1e-5f);

    // LN1 apply + gelu -> Hw (bf16 [px][ch], aliases Xw region)
    unsigned short* Hw = Xw;
    #pragma unroll
    for (int m = 0; m < 8; ++m) {
        const f32x4 gv = *reinterpret_cast<const f32x4*>(g1  + m * 16 + h * 4);
        const f32x4 bv = *reinterpret_cast<const f32x4*>(be1 + m * 16 + h * 4);
        u16x4 pk;
        #pragma unroll
        for (int r = 0; r < 4; ++r) {
            float v = (acc1[m][r] - mean1) * rstd1;
            v = v * gv[r] + bv[r];
            pk[r] = f2bf(gelu_f(v));
        }
        *reinterpret_cast<u16x4*>(&Hw[l15 * SH + m * 16 + h * 4]) = pk;
    }
    wave_lds_fence();   // Hw writes complete before own reads

    // ---- GEMM2: Y(256 x 16px) = W2(256x128) @ Hw(128x16) ----
    f32x4 acc2[16];
    #pragma unroll
    for (int m = 0; m < 16; ++m) acc2[m] = vzero;

    #pragma unroll
    for (int ks = 0; ks < 4; ++ks) {
        const int kb = ks * 32 + h * 8;
        const short4v blo = *reinterpret_cast<const short4v*>(&Hw[l15 * SH + kb]);
        const short4v bhi = *reinterpret_cast<const short4v*>(&Hw[l15 * SH + kb + 4]);
        const short8 bf = __builtin_shufflevector(blo, bhi, 0,1,2,3,4,5,6,7);
        #pragma unroll
        for (int half = 0; half < 2; ++half) {
            short8 a[8];
            #pragma unroll
            for (int m2 = 0; m2 < 8; ++m2) {
                const int row = (half * 8 + m2) * 16 + l15;
                if constexpr (USE_WS) {
                    a[m2] = *reinterpret_cast<const short8*>(W2b + (size_t)row * HC + kb);
                } else {
                    const float* wp = W2 + (size_t)row * HC + kb;
                    const f32x4 f0 = *reinterpret_cast<const f32x4*>(wp);
                    const f32x4 f1 = *reinterpret_cast<const f32x4*>(wp + 4);
                    #pragma unroll
                    for (int e = 0; e < 4; ++e) { a[m2][e] = (short)f2bf(f0[e]); a[m2][4+e] = (short)f2bf(f1[e]); }
                }
            }
            #pragma unroll
            for (int m2 = 0; m2 < 8; ++m2)
                acc2[half * 8 + m2] = __builtin_amdgcn_mfma_f32_16x16x32_bf16(a[m2], bf, acc2[half * 8 + m2], 0, 0, 0);
        }
    }

    // ---- bias2 + wave-local LN2 (256 ch of px l15) ----
    float s2 = 0.f, q2 = 0.f;
    #pragma unroll
    for (int m = 0; m < 16; ++m) {
        acc2[m] += *reinterpret_cast<const f32x4*>(b2 + m * 16 + h * 4);
        #pragma unroll
        for (int r = 0; r < 4; ++r) { const float v = acc2[m][r]; s2 += v; q2 += v * v; }
    }
    s2 += __shfl_xor(s2, 16); s2 += __shfl_xor(s2, 32);
    q2 += __shfl_xor(q2, 16); q2 += __shfl_xor(q2, 32);
    const float mean2 = s2 * (1.0f / C_IN);
    const float rstd2 = rsqrtf(q2 * (1.0f / C_IN) - mean2 * mean2 + 1e-5f);

    // ---- epilogue: LN2 apply + residual + gelu, scalar 64B-run stores,
    //      residual prefetched one 4-m chunk ahead ----
    const float* xrp = xb + wv * 16 + l15;
    float*       orp = ob + wv * 16 + l15;
    float rbuf[2][16];
    #pragma unroll
    for (int i = 0; i < 16; ++i) {
        const int m = i >> 2, r = i & 3;
        rbuf[0][i] = xrp[(size_t)(m * 16 + h * 4 + r) * HW];
    }
    #pragma unroll
    for (int mc = 0; mc < 4; ++mc) {
        if (mc < 3) {
            #pragma unroll
            for (int i = 0; i < 16; ++i) {
                const int m = (mc + 1) * 4 + (i >> 2), r = i & 3;
                rbuf[(mc + 1) & 1][i] = xrp[(size_t)(m * 16 + h * 4 + r) * HW];
            }
        }
        #pragma unroll
        for (int mi = 0; mi < 4; ++mi) {
            const int m = mc * 4 + mi;
            const f32x4 gv = *reinterpret_cast<const f32x4*>(g2  + m * 16 + h * 4);
            const f32x4 bv = *reinterpret_cast<const f32x4*>(be2 + m * 16 + h * 4);
            #pragma unroll
            for (int r = 0; r < 4; ++r) {
                float v = (acc2[m][r] - mean2) * rstd2;
                v = v * gv[r] + bv[r];
                v += rbuf[mc & 1][mi * 4 + r];
                orp[(size_t)(m * 16 + h * 4 + r) * HW] = gelu_f(v);
            }
        }
    }
}

extern "C" void kernel_launch(void* const* d_in, const int* in_sizes, int n_in,
                              void* d_out, int out_size, void* d_ws, size_t ws_size,
                              hipStream_t stream) {
    const float* x   = (const float*)d_in[0];
    const float* W1  = (const float*)d_in[1];
    const float* b1  = (const float*)d_in[2];
    const float* g1  = (const float*)d_in[3];
    const float* be1 = (const float*)d_in[4];
    const float* W2  = (const float*)d_in[5];
    const float* b2  = (const float*)d_in[6];
    const float* g2  = (const float*)d_in[7];
    const float* be2 = (const float*)d_in[8];
    float* out = (float*)d_out;

    const size_t need = (size_t)(HC * C_IN + C_IN * HC) * sizeof(unsigned short);
    if (ws_size >= need) {
        unsigned short* W1b = (unsigned short*)d_ws;
        unsigned short* W2b = W1b + HC * C_IN;
        convert_weights<<<128, 256, 0, stream>>>(W1, W2, W1b, W2b);
        fused_mlp<true><<<1024, 256, 0, stream>>>(x, W1, b1, g1, be1, W2, b2, g2, be2, W1b, W2b, out);
    } else {
        fused_mlp<false><<<1024, 256, 0, stream>>>(x, W1, b1, g1, be1, W2, b2, g2, be2, nullptr, nullptr, out);
    }
}

// Round 8
// 57.886 us; speedup vs baseline: 1.6604x; 1.6604x over previous
//
#include <hip/hip_runtime.h>

#define C_IN 256
#define HC   128
#define HW   4096
#define TP   64

#define SX 260      // u16 stride, X LDS rows [pixel][k] (mult of 4 -> 8B-aligned u16x4)
#define SH 132      // u16 stride, H LDS rows
#define SO 68       // f32 stride, out-staging rows. MUST be >= TP(64)+pad!
                    // R6/R7 FAIL ROOT CAUSE: SO=36 (stale from TP=32 kernel) -> OOB LDS.

typedef __attribute__((ext_vector_type(8))) short short8;
typedef __attribute__((ext_vector_type(4))) short short4v;
typedef __attribute__((ext_vector_type(4))) float f32x4;
typedef __attribute__((ext_vector_type(2))) float f32x2;
typedef __attribute__((ext_vector_type(4))) unsigned short u16x4;

__device__ __forceinline__ unsigned short f2bf(float f) {
    union { float f; unsigned int u; } v; v.f = f;
    return (unsigned short)((v.u + 0x7FFFu + ((v.u >> 16) & 1u)) >> 16);
}

// tanh-form GELU via exp2: max |err| vs exact-erf gelu ~3e-3 << 0.1456 threshold.
__device__ __forceinline__ float gelu_f(float v) {
    const float u = v * (0.7978845608028654f + 0.035677408136300125f * v * v);
    const float e = exp2f(u * 2.8853900817779268f);   // e^(2u)
    const float t = 1.0f - 2.0f * __builtin_amdgcn_rcpf(e + 1.0f);
    return 0.5f * v * (1.0f + t);
}

// Drain-free block barrier, bidirectional compiler fence.
// Never drains vmcnt: global loads stay in flight across the barrier.
__device__ __forceinline__ void block_sync() {
    asm volatile("s_waitcnt lgkmcnt(0)" ::: "memory");
    __builtin_amdgcn_s_barrier();
    asm volatile("" ::: "memory");
    __builtin_amdgcn_sched_barrier(0);
}

// Wave-local LDS ordering for the per-wave Ob buffer (validated in R4).
__device__ __forceinline__ void wave_lds_fence() {
    asm volatile("s_waitcnt lgkmcnt(0)" ::: "memory");
}

__global__ void convert_weights(const float* __restrict__ W1, const float* __restrict__ W2,
                                unsigned short* __restrict__ W1b, unsigned short* __restrict__ W2b) {
    int i = blockIdx.x * blockDim.x + threadIdx.x;
    if (i < HC * C_IN) { W1b[i] = f2bf(W1[i]); W2b[i] = f2bf(W2[i]); }
}

union SmemU {
    unsigned short Xs[TP * SX];                                     // 33280 B
    struct { unsigned short Hs[TP * SH]; float Ob[4][16][SO]; } u2; // 16896 + 17408
};

template<bool USE_WS>
__global__ __launch_bounds__(256, 4) void fused_mlp(
    const float* __restrict__ x,
    const float* __restrict__ W1, const float* __restrict__ b1,
    const float* __restrict__ g1, const float* __restrict__ be1,
    const float* __restrict__ W2, const float* __restrict__ b2,
    const float* __restrict__ g2, const float* __restrict__ be2,
    const unsigned short* __restrict__ W1b, const unsigned short* __restrict__ W2b,
    float* __restrict__ out)
{
    __shared__ alignas(16) SmemU sm;
    __shared__ float red[4][TP][2];

    const int tid = threadIdx.x;
    const int wv  = tid >> 6;
    const int l   = tid & 63;
    const int l15 = l & 15;
    const int kg  = l >> 4;     // 0..3

    const int bid = blockIdx.x;
    const int b   = bid >> 6;
    const int p0  = (bid & 63) * TP;
    const float* xb = x   + (size_t)b * (C_IN * HW) + p0;
    float*       ob = out + (size_t)b * (C_IN * HW) + p0;

    // ---- staging: issue ALL 16 loads; write half-0 (c<128) now, half-1 after GEMM1 ks0..3 ----
    const int g  = l15;                // pixel quad: px = g*4+jj (0..63)
    const int cs = wv * 16 + kg * 4;   // channel subquad base within a 64-ch round
    f32x4 v0[8], v1[8];
    #pragma unroll
    for (int rnd = 0; rnd < 2; ++rnd)
        #pragma unroll
        for (int j = 0; j < 4; ++j)
            v0[rnd * 4 + j] = *reinterpret_cast<const f32x4*>(xb + (size_t)(rnd * 64 + cs + j) * HW + g * 4);
    #pragma unroll
    for (int rnd = 0; rnd < 2; ++rnd)
        #pragma unroll
        for (int j = 0; j < 4; ++j)
            v1[rnd * 4 + j] = *reinterpret_cast<const f32x4*>(xb + (size_t)((rnd + 2) * 64 + cs + j) * HW + g * 4);
    #pragma unroll
    for (int rnd = 0; rnd < 2; ++rnd) {
        const int c0 = rnd * 64 + cs;
        #pragma unroll
        for (int jj = 0; jj < 4; ++jj) {
            u16x4 pk;
            #pragma unroll
            for (int j = 0; j < 4; ++j) pk[j] = f2bf(v0[rnd * 4 + j][jj]);
            *reinterpret_cast<u16x4*>(&sm.Xs[(size_t)(g * 4 + jj) * SX + c0]) = pk;
        }
    }
    block_sync();   // b1: half-0 visible; half-1 global loads still in flight

    // ---- GEMM1: H(128x64) = W1(128x256) @ X(256x64), K split 2x128 ----
    f32x4 acc1[2][4];
    const f32x4 vzero = {0.f, 0.f, 0.f, 0.f};
    #pragma unroll
    for (int mt = 0; mt < 2; ++mt)
        #pragma unroll
        for (int nt = 0; nt < 4; ++nt) acc1[mt][nt] = vzero;

    const int r0 = wv * 32;
    #pragma unroll
    for (int ks = 0; ks < 4; ++ks) {
        const int kb = ks * 32 + kg * 8;
        short8 a[2]; short4v blo[4], bhi[4];
        #pragma unroll
        for (int mt = 0; mt < 2; ++mt) {
            const int row = r0 + mt * 16 + l15;
            if constexpr (USE_WS) {
                a[mt] = *reinterpret_cast<const short8*>(W1b + (size_t)row * C_IN + kb);
            } else {
                const float* wp = W1 + (size_t)row * C_IN + kb;
                const f32x4 f0 = *reinterpret_cast<const f32x4*>(wp);
                const f32x4 f1 = *reinterpret_cast<const f32x4*>(wp + 4);
                #pragma unroll
                for (int e = 0; e < 4; ++e) { a[mt][e] = (short)f2bf(f0[e]); a[mt][4+e] = (short)f2bf(f1[e]); }
            }
        }
        #pragma unroll
        for (int nt = 0; nt < 4; ++nt) {
            const unsigned short* p = &sm.Xs[(size_t)(nt * 16 + l15) * SX + kb];
            blo[nt] = *reinterpret_cast<const short4v*>(p);
            bhi[nt] = *reinterpret_cast<const short4v*>(p + 4);
        }
        #pragma unroll
        for (int mt = 0; mt < 2; ++mt)
            #pragma unroll
            for (int nt = 0; nt < 4; ++nt) {
                const short8 bf = __builtin_shufflevector(blo[nt], bhi[nt], 0,1,2,3,4,5,6,7);
                acc1[mt][nt] = __builtin_amdgcn_mfma_f32_16x16x32_bf16(a[mt], bf, acc1[mt][nt], 0, 0, 0);
            }
    }

    // write half-1 of X (loads overlapped with ks0..3 above)
    #pragma unroll
    for (int rnd = 0; rnd < 2; ++rnd) {
        const int c0 = (rnd + 2) * 64 + cs;
        #pragma unroll
        for (int jj = 0; jj < 4; ++jj) {
            u16x4 pk;
            #pragma unroll
            for (int j = 0; j < 4; ++j) pk[j] = f2bf(v1[rnd * 4 + j][jj]);
            *reinterpret_cast<u16x4*>(&sm.Xs[(size_t)(g * 4 + jj) * SX + c0]) = pk;
        }
    }
    block_sync();   // b2: half-1 visible

    #pragma unroll
    for (int ks = 4; ks < 8; ++ks) {
        const int kb = ks * 32 + kg * 8;
        short8 a[2]; short4v blo[4], bhi[4];
        #pragma unroll
        for (int mt = 0; mt < 2; ++mt) {
            const int row = r0 + mt * 16 + l15;
            if constexpr (USE_WS) {
                a[mt] = *reinterpret_cast<const short8*>(W1b + (size_t)row * C_IN + kb);
            } else {
                const float* wp = W1 + (size_t)row * C_IN + kb;
                const f32x4 f0 = *reinterpret_cast<const f32x4*>(wp);
                const f32x4 f1 = *reinterpret_cast<const f32x4*>(wp + 4);
                #pragma unroll
                for (int e = 0; e < 4; ++e) { a[mt][e] = (short)f2bf(f0[e]); a[mt][4+e] = (short)f2bf(f1[e]); }
            }
        }
        #pragma unroll
        for (int nt = 0; nt < 4; ++nt) {
            const unsigned short* p = &sm.Xs[(size_t)(nt * 16 + l15) * SX + kb];
            blo[nt] = *reinterpret_cast<const short4v*>(p);
            bhi[nt] = *reinterpret_cast<const short4v*>(p + 4);
        }
        #pragma unroll
        for (int mt = 0; mt < 2; ++mt)
            #pragma unroll
            for (int nt = 0; nt < 4; ++nt) {
                const short8 bf = __builtin_shufflevector(blo[nt], bhi[nt], 0,1,2,3,4,5,6,7);
                acc1[mt][nt] = __builtin_amdgcn_mfma_f32_16x16x32_bf16(a[mt], bf, acc1[mt][nt], 0, 0, 0);
            }
    }

    // bias1 + LN1 partials
    #pragma unroll
    for (int mt = 0; mt < 2; ++mt) {
        const f32x4 bias = *reinterpret_cast<const f32x4*>(b1 + r0 + mt * 16 + kg * 4);
        #pragma unroll
        for (int nt = 0; nt < 4; ++nt) acc1[mt][nt] += bias;
    }
    #pragma unroll
    for (int nt = 0; nt < 4; ++nt) {
        float s = 0.f, q = 0.f;
        #pragma unroll
        for (int mt = 0; mt < 2; ++mt)
            #pragma unroll
            for (int r = 0; r < 4; ++r) { const float v = acc1[mt][nt][r]; s += v; q += v * v; }
        s += __shfl_xor(s, 16); s += __shfl_xor(s, 32);
        q += __shfl_xor(q, 16); q += __shfl_xor(q, 32);
        if (kg == 0) { red[wv][nt * 16 + l15][0] = s; red[wv][nt * 16 + l15][1] = q; }
    }
    block_sync();   // b3: red ready; all Xs reads retired -> Hs (alias) writable

    // LN1 apply + gelu -> Hs
    {
        f32x4 gm[2], bt[2];
        #pragma unroll
        for (int mt = 0; mt < 2; ++mt) {
            gm[mt] = *reinterpret_cast<const f32x4*>(g1  + r0 + mt * 16 + kg * 4);
            bt[mt] = *reinterpret_cast<const f32x4*>(be1 + r0 + mt * 16 + kg * 4);
        }
        #pragma unroll
        for (int nt = 0; nt < 4; ++nt) {
            const int col = nt * 16 + l15;
            float s = 0.f, q = 0.f;
            #pragma unroll
            for (int w2 = 0; w2 < 4; ++w2) { s += red[w2][col][0]; q += red[w2][col][1]; }
            const float mean = s * (1.0f / HC);
            const float rstd = rsqrtf(q * (1.0f / HC) - mean * mean + 1e-5f);
            #pragma unroll
            for (int mt = 0; mt < 2; ++mt) {
                u16x4 pk;
                #pragma unroll
                for (int r = 0; r < 4; ++r) {
                    float v = (acc1[mt][nt][r] - mean) * rstd;
                    v = v * gm[mt][r] + bt[mt][r];
                    pk[r] = f2bf(gelu_f(v));
                }
                *reinterpret_cast<u16x4*>(&sm.u2.Hs[(size_t)col * SH + r0 + mt * 16 + kg * 4]) = pk;
            }
        }
    }
    block_sync();   // b4: Hs ready

    // early residual issue for epilogue mt=0 (hidden under GEMM2; barriers don't drain vmcnt)
    const int r2 = wv * 64;
    f32x4 xp[4];
    #pragma unroll
    for (int m = 0; m < 4; ++m)
        xp[m] = *reinterpret_cast<const f32x4*>(xb + (size_t)(r2 + kg + 4 * m) * HW + l15 * 4);

    // ---- GEMM2: Y(256x64) = W2(256x128) @ H(128x64) ----
    f32x4 acc2[4][4];
    #pragma unroll
    for (int mt = 0; mt < 4; ++mt)
        #pragma unroll
        for (int nt = 0; nt < 4; ++nt) acc2[mt][nt] = vzero;

    #pragma unroll
    for (int ks = 0; ks < 4; ++ks) {
        const int kb = ks * 32 + kg * 8;
        short4v blo[4], bhi[4];
        #pragma unroll
        for (int nt = 0; nt < 4; ++nt) {
            const unsigned short* p = &sm.u2.Hs[(size_t)(nt * 16 + l15) * SH + kb];
            blo[nt] = *reinterpret_cast<const short4v*>(p);
            bhi[nt] = *reinterpret_cast<const short4v*>(p + 4);
        }
        #pragma unroll
        for (int half = 0; half < 2; ++half) {
            short8 a[2];
            #pragma unroll
            for (int m2 = 0; m2 < 2; ++m2) {
                const int row = r2 + (half * 2 + m2) * 16 + l15;
                if constexpr (USE_WS) {
                    a[m2] = *reinterpret_cast<const short8*>(W2b + (size_t)row * HC + kb);
                } else {
                    const float* wp = W2 + (size_t)row * HC + kb;
                    const f32x4 f0 = *reinterpret_cast<const f32x4*>(wp);
                    const f32x4 f1 = *reinterpret_cast<const f32x4*>(wp + 4);
                    #pragma unroll
                    for (int e = 0; e < 4; ++e) { a[m2][e] = (short)f2bf(f0[e]); a[m2][4+e] = (short)f2bf(f1[e]); }
                }
            }
            #pragma unroll
            for (int m2 = 0; m2 < 2; ++m2)
                #pragma unroll
                for (int nt = 0; nt < 4; ++nt) {
                    const short8 bf = __builtin_shufflevector(blo[nt], bhi[nt], 0,1,2,3,4,5,6,7);
                    acc2[half * 2 + m2][nt] = __builtin_amdgcn_mfma_f32_16x16x32_bf16(a[m2], bf, acc2[half * 2 + m2][nt], 0, 0, 0);
                }
        }
    }

    // bias2 + LN2 partials
    #pragma unroll
    for (int mt = 0; mt < 4; ++mt) {
        const f32x4 bias = *reinterpret_cast<const f32x4*>(b2 + r2 + mt * 16 + kg * 4);
        #pragma unroll
        for (int nt = 0; nt < 4; ++nt) acc2[mt][nt] += bias;
    }
    #pragma unroll
    for (int nt = 0; nt < 4; ++nt) {
        float s = 0.f, q = 0.f;
        #pragma unroll
        for (int mt = 0; mt < 4; ++mt)
            #pragma unroll
            for (int r = 0; r < 4; ++r) { const float v = acc2[mt][nt][r]; s += v; q += v * v; }
        s += __shfl_xor(s, 16); s += __shfl_xor(s, 32);
        q += __shfl_xor(q, 16); q += __shfl_xor(q, 32);
        if (kg == 0) { red[wv][nt * 16 + l15][0] = s; red[wv][nt * 16 + l15][1] = q; }
    }
    block_sync();   // b5: red2 ready; Hs reads retired -> Ob (alias) writable

    float mean2[4], rstd2[4];
    #pragma unroll
    for (int nt = 0; nt < 4; ++nt) {
        const int col = nt * 16 + l15;
        float s = 0.f, q = 0.f;
        #pragma unroll
        for (int w2 = 0; w2 < 4; ++w2) { s += red[w2][col][0]; q += red[w2][col][1]; }
        mean2[nt] = s * (1.0f / C_IN);
        rstd2[nt] = rsqrtf(q * (1.0f / C_IN) - mean2[nt] * mean2[nt] + 1e-5f);
    }

    // epilogue: per-wave LDS transpose, wave-local fences, residual prefetched one mt ahead
    #pragma unroll
    for (int mt = 0; mt < 4; ++mt) {
        const f32x4 gm = *reinterpret_cast<const f32x4*>(g2  + r2 + mt * 16 + kg * 4);
        const f32x4 bt = *reinterpret_cast<const f32x4*>(be2 + r2 + mt * 16 + kg * 4);
        #pragma unroll
        for (int nt = 0; nt < 4; ++nt) {
            #pragma unroll
            for (int r = 0; r < 4; ++r) {
                float v = (acc2[mt][nt][r] - mean2[nt]) * rstd2[nt];
                v = v * gm[r] + bt[r];
                sm.u2.Ob[wv][kg * 4 + r][nt * 16 + l15] = v;
            }
        }
        f32x4 xn[4];
        if (mt < 3) {
            #pragma unroll
            for (int m = 0; m < 4; ++m)
                xn[m] = *reinterpret_cast<const f32x4*>(xb + (size_t)(r2 + (mt + 1) * 16 + kg + 4 * m) * HW + l15 * 4);
        }
        wave_lds_fence();
        #pragma unroll
        for (int m = 0; m < 4; ++m) {
            const int rl  = kg + 4 * m;
            const int row = r2 + mt * 16 + rl;
            const float* op = &sm.u2.Ob[wv][rl][l15 * 4];
            const f32x2 ylo = *reinterpret_cast<const f32x2*>(op);
            const f32x2 yhi = *reinterpret_cast<const f32x2*>(op + 2);
            f32x4 o4;
            o4[0] = gelu_f(ylo[0] + xp[m][0]);
            o4[1] = gelu_f(ylo[1] + xp[m][1]);
            o4[2] = gelu_f(yhi[0] + xp[m][2]);
            o4[3] = gelu_f(yhi[1] + xp[m][3]);
            *reinterpret_cast<f32x4*>(ob + (size_t)row * HW + l15 * 4) = o4;
        }
        #pragma unroll
        for (int m = 0; m < 4; ++m) xp[m] = xn[m];
        if (mt < 3) wave_lds_fence();   // WAR: Ob reads done before next mt's writes
    }
}

extern "C" void kernel_launch(void* const* d_in, const int* in_sizes, int n_in,
                              void* d_out, int out_size, void* d_ws, size_t ws_size,
                              hipStream_t stream) {
    const float* x   = (const float*)d_in[0];
    const float* W1  = (const float*)d_in[1];
    const float* b1  = (const float*)d_in[2];
    const float* g1  = (const float*)d_in[3];
    const float* be1 = (const float*)d_in[4];
    const float* W2  = (const float*)d_in[5];
    const float* b2  = (const float*)d_in[6];
    const float* g2  = (const float*)d_in[7];
    const float* be2 = (const float*)d_in[8];
    float* out = (float*)d_out;

    const size_t need = (size_t)(HC * C_IN + C_IN * HC) * sizeof(unsigned short);
    if (ws_size >= need) {
        unsigned short* W1b = (unsigned short*)d_ws;
        unsigned short* W2b = W1b + HC * C_IN;
        convert_weights<<<128, 256, 0, stream>>>(W1, W2, W1b, W2b);
        fused_mlp<true><<<1024, 256, 0, stream>>>(x, W1, b1, g1, be1, W2, b2, g2, be2, W1b, W2b, out);
    } else {
        fused_mlp<false><<<1024, 256, 0, stream>>>(x, W1, b1, g1, be1, W2, b2, g2, be2, nullptr, nullptr, out);
    }
}